// Round 1
// 631.491 us; speedup vs baseline: 1.0031x; 1.0031x over previous
//
#include <hip/hip_runtime.h>
#include <math.h>

#define N_NODESC 100000
#define N_EDGESC 1600000
#define E_TOT    1700000   // incl. self loops
#define IN_CH    500
#define KPAD     512
#define D1 64
#define H1C 8
#define D2 24
#define H2C 8
#define NBLK 391           // ceil(N_NODESC/256)
#define NBKT 391           // dst buckets of 256 nodes
#define EPB  4096          // edges per k_part block

typedef __attribute__((ext_vector_type(8))) short short8;
typedef __attribute__((ext_vector_type(4))) float f32x4;

__device__ inline short f2bf(float f) {            // RTNE fp32 -> bf16
    unsigned u = __float_as_uint(f);
    u += 0x7fffu + ((u >> 16) & 1u);
    return (short)(u >> 16);
}
// pack two fp32 -> two bf16 (round-half-away) in one perm
__device__ inline unsigned pkbf(float a, float b) {
    const unsigned ua = __float_as_uint(a) + 0x8000u;
    const unsigned ub = __float_as_uint(b) + 0x8000u;
    return __builtin_amdgcn_perm(ub, ua, 0x07060302u);  // lo16=a_bf, hi16=b_bf
}
__device__ inline float bflo(unsigned u) { return __uint_as_float(u << 16); }
__device__ inline float bfhi(unsigned u) { return __uint_as_float(u & 0xffff0000u); }

// ================= degree histogram =================
__global__ __launch_bounds__(256) void k_hist(const int* __restrict__ ei,
                                              int* __restrict__ deg) {
    const int e = blockIdx.x * 256 + threadIdx.x;
    if (e >= E_TOT) return;
    const int d = (e < N_EDGESC) ? ei[N_EDGESC + e] : (e - N_EDGESC);
    atomicAdd(deg + d, 1);
}

__global__ __launch_bounds__(256) void k_bsum(const int* __restrict__ deg,
                                              int* __restrict__ bsum) {
    const int i = blockIdx.x * 256 + threadIdx.x;
    int v = (i < N_NODESC) ? deg[i] : 0;
#pragma unroll
    for (int m = 1; m < 64; m <<= 1) v += __shfl_xor(v, m, 64);
    __shared__ int ws[4];
    if ((threadIdx.x & 63) == 0) ws[threadIdx.x >> 6] = v;
    __syncthreads();
    if (threadIdx.x == 0) bsum[blockIdx.x] = ws[0] + ws[1] + ws[2] + ws[3];
}

__global__ __launch_bounds__(512) void k_bscan(const int* __restrict__ bsum,
                                               int* __restrict__ boff) {
    __shared__ int sm[512];
    const int t = threadIdx.x;
    const int v = (t < NBLK) ? bsum[t] : 0;
    sm[t] = v;
    __syncthreads();
    for (int d = 1; d < 512; d <<= 1) {
        int u = (t >= d) ? sm[t - d] : 0;
        __syncthreads();
        sm[t] += u;
        __syncthreads();
    }
    if (t < NBLK) boff[t] = sm[t] - v;   // exclusive
}

__global__ __launch_bounds__(256) void k_off(const int* __restrict__ deg,
                                             const int* __restrict__ boff,
                                             int* __restrict__ off,
                                             int* __restrict__ gcur) {
    __shared__ int sm[256];
    const int t = threadIdx.x;
    const int i = blockIdx.x * 256 + t;
    const int v = (i < N_NODESC) ? deg[i] : 0;
    sm[t] = v;
    __syncthreads();
    for (int d = 1; d < 256; d <<= 1) {
        int u = (t >= d) ? sm[t - d] : 0;
        __syncthreads();
        sm[t] += u;
        __syncthreads();
    }
    if (i < N_NODESC) {
        const int ex = boff[blockIdx.x] + sm[t] - v;
        off[i] = ex;
        if ((i & 255) == 0) gcur[i >> 8] = ex;   // bucket cursor init
    }
    if (i == 0) off[N_NODESC] = E_TOT;
}

// ================= phase A: partition edges into 391 dst-buckets =================
// tmp packed: src (17b) | dstLow (8b) << 17
__global__ __launch_bounds__(256) void k_part(const int* __restrict__ ei,
                                              int* __restrict__ gcur,
                                              int* __restrict__ tmp) {
    __shared__ int hist[NBKT];
    __shared__ int lbase[NBKT];
    const int t = threadIdx.x;
    const int e0 = blockIdx.x * EPB;
    for (int i = t; i < NBKT; i += 256) hist[i] = 0;
    __syncthreads();
    int se[16], de[16], mo[16];
#pragma unroll
    for (int i = 0; i < 16; i++) {
        const int e = e0 + i * 256 + t;
        int s = -1, d = 0;
        if (e < E_TOT) {
            if (e < N_EDGESC) { s = ei[e]; d = ei[N_EDGESC + e]; }
            else { s = d = e - N_EDGESC; }
        }
        se[i] = s; de[i] = d;
        mo[i] = (s >= 0) ? atomicAdd(&hist[d >> 8], 1) : 0;
    }
    __syncthreads();
    for (int i = t; i < NBKT; i += 256)
        lbase[i] = hist[i] ? atomicAdd(&gcur[i], hist[i]) : 0;
    __syncthreads();
#pragma unroll
    for (int i = 0; i < 16; i++) {
        if (se[i] >= 0)
            tmp[lbase[de[i] >> 8] + mo[i]] = se[i] | ((de[i] & 255) << 17);
    }
}

// ================= phase B: within-bucket scatter to CSR =================
__global__ __launch_bounds__(256) void k_bucket(const int* __restrict__ off,
                                                const int* __restrict__ tmp,
                                                int* __restrict__ srt) {
    __shared__ int lcur[256];
    const int nodeBase = blockIdx.x << 8;
    const int t = threadIdx.x;
    const int nNodes = min(256, N_NODESC - nodeBase);
    if (t < nNodes) lcur[t] = off[nodeBase + t];
    const int start = off[nodeBase];
    const int end = off[nodeBase + nNodes];
    __syncthreads();
    for (int k = start + t; k < end; k += 256) {
        const int p = tmp[k];
        const int pos = atomicAdd(&lcur[p >> 17], 1);
        srt[pos] = p & 0x1FFFF;
    }
}

// ================= W1 -> bf16 transposed, K zero-padded to 512 =================
__global__ __launch_bounds__(256) void k_wprep(const float* __restrict__ W1,
                                               short* __restrict__ wT) {
    const int idx = blockIdx.x * 256 + threadIdx.x;   // 64*512 = 32768
    if (idx >= D1 * KPAD) return;
    const int n = idx >> 9, k = idx & (KPAD - 1);
    wT[idx] = (k < IN_CH) ? f2bf(W1[k * D1 + n]) : (short)0;
}

// ================= K1: xw1 = x @ W1 via bf16 MFMA, fused al1 epilogue =================
// xw1 stored as bf16 (halves the gather traffic in k_gat1); attention logits
// al1s/al1d computed here from the fp32 accumulators (exact path preserved).
__global__ __launch_bounds__(256) void k_gemm1(const float* __restrict__ x,
                                               const short* __restrict__ wT,
                                               const float* __restrict__ a1s,
                                               const float* __restrict__ a1d,
                                               short* __restrict__ xw1b,
                                               float* __restrict__ al1s,
                                               float* __restrict__ al1d) {
    __shared__ short xs[32 * 520];
    const int t = threadIdx.x;
    const int rowBase = blockIdx.x * 32;        // 3125 * 32 == 100000 exactly
    const int r = t >> 3, j = t & 7;
    const float* xr = x + (long)(rowBase + r) * IN_CH;
    short* xrow = xs + r * 520;
#pragma unroll
    for (int i = 0; i < 16; i++) {
        const int c = j + i * 8;                 // float4 index, 125 per row
        if (c < 125) {
            const float4 v = *(const float4*)(xr + c * 4);
            const unsigned lo = pkbf(v.x, v.y);
            const unsigned hi = pkbf(v.z, v.w);
            *(uint2*)(xrow + c * 4) = make_uint2(lo, hi);
        }
    }
    if (j < 6) *(unsigned*)(xrow + 500 + j * 2) = 0u;   // zero halfs 500..511
    __syncthreads();

    const int lane = t & 63, wv = t >> 6;
    const int m = lane & 15, kg = lane >> 4;
    f32x4 acc[2];
    acc[0] = (f32x4){0.f, 0.f, 0.f, 0.f};
    acc[1] = (f32x4){0.f, 0.f, 0.f, 0.f};
    const short* wcol = wT + (wv * 16 + m) * KPAD;
#pragma unroll
    for (int k0 = 0; k0 < KPAD; k0 += 32) {
        const short8 bf = *(const short8*)(wcol + k0 + kg * 8);
#pragma unroll
        for (int mf = 0; mf < 2; mf++) {
            const short8 af = *(const short8*)(xs + (mf * 16 + m) * 520 + k0 + kg * 8);
            acc[mf] = __builtin_amdgcn_mfma_f32_16x16x32_bf16(af, bf, acc[mf], 0, 0, 0);
        }
    }
    // C layout: row = kg*4 + jj (within 16-row frag), col = wv*16 + m
    const int col = wv * 16 + m;
    const float as = a1s[col];     // a1_src flat (H,C): index == col
    const float ad = a1d[col];
    const int hh = wv * 2 + (m >> 3);
#pragma unroll
    for (int mf = 0; mf < 2; mf++) {
#pragma unroll
        for (int jj = 0; jj < 4; jj++) {
            const int row = rowBase + mf * 16 + kg * 4 + jj;
            const float v = acc[mf][jj];
            xw1b[(long)row * D1 + col] = f2bf(v);
            // 8-lane (m&7) reduce -> per-(row,head) logits
            float ts = v * as, td = v * ad;
            ts += __shfl_xor(ts, 1, 64); td += __shfl_xor(td, 1, 64);
            ts += __shfl_xor(ts, 2, 64); td += __shfl_xor(td, 2, 64);
            ts += __shfl_xor(ts, 4, 64); td += __shfl_xor(td, 4, 64);
            if ((m & 7) == 0) {
                al1s[row * 8 + hh] = ts;
                al1d[row * 8 + hh] = td;
            }
        }
    }
}

// ================= K3: gather-aggregate layer 1 + fused layer-2 projection =================
// Wave computes hmid row in-register, pushes it straight through hmid @ W2
// (64x24) in LDS, writes only xw2 / al2s / al2d. hmid never touches HBM.
__global__ __launch_bounds__(256) void k_gat1(const int* __restrict__ off,
                                              const int* __restrict__ srt_src,
                                              const float* __restrict__ al1s,
                                              const float* __restrict__ al1d,
                                              const short* __restrict__ xw1b,
                                              const float* __restrict__ b1,
                                              const float* __restrict__ W2,
                                              const float* __restrict__ a2s,
                                              const float* __restrict__ a2d,
                                              float* __restrict__ xw2,
                                              float* __restrict__ al2s,
                                              float* __restrict__ al2d) {
    __shared__ float w2s[D1 * D2];
    __shared__ float hrow[4][D1];
    const int tid = threadIdx.x;
    for (int i = tid; i < D1 * D2; i += 256) w2s[i] = W2[i];
    __syncthreads();

    const int lane = tid & 63;
    const int wid = tid >> 6;
    const int n = blockIdx.x * 4 + wid;   // N_NODESC % 4 == 0
    const int esub = lane >> 4;
    const int q = lane & 15;
    const int h = q >> 1;

    const float ald = al1d[n * 8 + h];
    const int kend = off[n + 1];

    float4 acc = make_float4(0.f, 0.f, 0.f, 0.f);
    float ssum = 0.f;
    for (int k = off[n] + esub; k < kend; k += 4) {
        const int s = srt_src[k];
        float ev = al1s[s * 8 + h] + ald;
        ev = ev > 0.f ? ev : 0.2f * ev;
        const float ex = expf(ev);
        const uint2 v = *(const uint2*)(xw1b + (long)s * D1 + q * 4);  // 4 bf16, 128B/row
        acc.x += ex * bflo(v.x); acc.y += ex * bfhi(v.x);
        acc.z += ex * bflo(v.y); acc.w += ex * bfhi(v.y);
        ssum += ex;
    }
#pragma unroll
    for (int mm = 16; mm < 64; mm <<= 1) {
        acc.x += __shfl_xor(acc.x, mm, 64);
        acc.y += __shfl_xor(acc.y, mm, 64);
        acc.z += __shfl_xor(acc.z, mm, 64);
        acc.w += __shfl_xor(acc.w, mm, 64);
        ssum  += __shfl_xor(ssum,  mm, 64);
    }
    if (esub == 0) {
        const float inv = 1.0f / (ssum + 1e-16f);
        const float4 bb = *(const float4*)(b1 + q * 4);
        float4 rr;
        rr.x = acc.x * inv + bb.x; rr.x = rr.x > 0.f ? rr.x : expm1f(rr.x);
        rr.y = acc.y * inv + bb.y; rr.y = rr.y > 0.f ? rr.y : expm1f(rr.y);
        rr.z = acc.z * inv + bb.z; rr.z = rr.z > 0.f ? rr.z : expm1f(rr.z);
        rr.w = acc.w * inv + bb.w; rr.w = rr.w > 0.f ? rr.w : expm1f(rr.w);
        *(float4*)(&hrow[wid][q * 4]) = rr;   // wave-local LDS handoff
    }
    // o[j] = sum_c hrow[c]*W2[c][j]; c split over two 24-lane half-groups
    const int half = lane / 24;              // 0,1,2 (lanes 48-63 duplicate half 0)
    const int j2 = lane - half * 24;         // 0..23
    const int cb = (half == 1) ? 32 : 0;
    float o = 0.f;
#pragma unroll
    for (int c4 = 0; c4 < 8; c4++) {
        const float4 hv = *(const float4*)(&hrow[wid][cb + c4 * 4]);  // broadcast read
        const float* wr = w2s + (cb + c4 * 4) * D2 + j2;
        o += hv.x * wr[0] + hv.y * wr[D2] + hv.z * wr[2 * D2] + hv.w * wr[3 * D2];
    }
    const int src2 = (lane < 24) ? lane + 24 : lane;
    o += __shfl(o, src2, 64);                // lanes<24 hold the full 64-dot
    if (lane < 24) xw2[(long)n * D2 + lane] = o;
    const float ps = o * a2s[j2];
    const float pd = o * a2d[j2];
    const int hb = 3 * (lane & 7);
    const float s3 = __shfl(ps, hb, 64) + __shfl(ps, hb + 1, 64) + __shfl(ps, hb + 2, 64);
    const float d3 = __shfl(pd, hb, 64) + __shfl(pd, hb + 1, 64) + __shfl(pd, hb + 2, 64);
    if (lane < 8) {
        al2s[n * 8 + lane] = s3;
        al2d[n * 8 + lane] = d3;
    }
}

// ================= K5: gather-aggregate layer 2 + head-mean + softmax =================
__global__ __launch_bounds__(256) void k_gat2(const int* __restrict__ off,
                                              const int* __restrict__ srt_src,
                                              const float* __restrict__ al2s,
                                              const float* __restrict__ al2d,
                                              const float* __restrict__ xw2,
                                              const float* __restrict__ b2,
                                              float* __restrict__ out) {
    __shared__ float sm[4][24];
    const int tid = threadIdx.x;
    const int lane = tid & 63;
    const int wid = tid >> 6;
    const int n = blockIdx.x * 4 + wid;
    const int esub = lane / 24;          // 0,1,2
    const int j = lane - esub * 24;
    const int h = j / 3;

    float acc = 0.f, ssum = 0.f;
    if (esub < 2) {
        const float ald = al2d[n * 8 + h];
        const int kend = off[n + 1];
        for (int k = off[n] + esub; k < kend; k += 2) {
            const int s = srt_src[k];
            float ev = al2s[s * 8 + h] + ald;
            ev = ev > 0.f ? ev : 0.2f * ev;
            const float ex = expf(ev);
            acc += ex * xw2[(long)s * D2 + j];
            ssum += ex;
        }
    }
    acc  += __shfl_down(acc, 24, 64);
    ssum += __shfl_down(ssum, 24, 64);
    if (lane < 24) sm[wid][j] = acc / (ssum + 1e-16f);
    __syncthreads();
    float lg = 0.f;
    if (lane < 3) {
#pragma unroll
        for (int hh = 0; hh < 8; hh++) lg += sm[wid][hh * 3 + lane];
        lg = lg * 0.125f + b2[lane];
    }
    const float l0 = __shfl(lg, 0, 64);
    const float l1 = __shfl(lg, 1, 64);
    const float l2 = __shfl(lg, 2, 64);
    if (lane < 3) {
        const float m = fmaxf(l0, fmaxf(l1, l2));
        const float denom = expf(l0 - m) + expf(l1 - m) + expf(l2 - m);
        out[(long)n * 3 + lane] = expf(lg - m) / denom;
    }
}

extern "C" void kernel_launch(void* const* d_in, const int* in_sizes, int n_in,
                              void* d_out, int out_size, void* d_ws, size_t ws_size,
                              hipStream_t stream) {
    const float* x   = (const float*)d_in[0];
    const float* W1  = (const float*)d_in[1];
    const float* a1s = (const float*)d_in[2];
    const float* a1d = (const float*)d_in[3];
    const float* b1  = (const float*)d_in[4];
    const float* W2  = (const float*)d_in[5];
    const float* a2s = (const float*)d_in[6];
    const float* a2d = (const float*)d_in[7];
    const float* b2  = (const float*)d_in[8];
    const int*   ei  = (const int*)d_in[9];
    float* out = (float*)d_out;

    float* ws   = (float*)d_ws;
    float* xw2  = ws;                      // 2,400,000 floats (tmp overlays before k_gat1)
    float* al1s = xw2  + 2400000;          //   800,000
    float* al1d = al1s + 800000;           //   800,000
    float* al2s = al1d + 800000;           //   800,000
    float* al2d = al2s + 800000;           //   800,000
    short* xw1b = (short*)(al2d + 800000); // 6,400,000 shorts (bf16)
    int* deg    = (int*)(xw1b + 6400000);  //   100,000
    int* off    = deg + 100000;            //   100,001
    int* gcur   = off + 100001;            //   NBKT
    int* srt    = gcur + NBKT;             // 1,700,000
    int* bsum   = srt + 1700000;           //   NBLK
    int* boff   = bsum + NBLK;             //   NBLK
    short* wT   = (short*)(boff + NBLK);   //   64*512 halfs
    int* tmp    = (int*)xw2;               // 1,700,000 ints (packed src|dstLow<<17)

    hipMemsetAsync(deg, 0, (size_t)N_NODESC * sizeof(int), stream);

    const int EB = (E_TOT + 255) / 256;
    k_hist<<<EB, 256, 0, stream>>>(ei, deg);
    k_bsum<<<NBLK, 256, 0, stream>>>(deg, bsum);
    k_bscan<<<1, 512, 0, stream>>>(bsum, boff);
    k_off<<<NBLK, 256, 0, stream>>>(deg, boff, off, gcur);
    k_part<<<(E_TOT + EPB - 1) / EPB, 256, 0, stream>>>(ei, gcur, tmp);
    k_bucket<<<NBKT, 256, 0, stream>>>(off, tmp, srt);

    k_wprep<<<(D1 * KPAD + 255) / 256, 256, 0, stream>>>(W1, wT);
    k_gemm1<<<N_NODESC / 32, 256, 0, stream>>>(x, wT, a1s, a1d, xw1b, al1s, al1d);
    k_gat1<<<N_NODESC / 4, 256, 0, stream>>>(off, srt, al1s, al1d, xw1b, b1,
                                             W2, a2s, a2d, xw2, al2s, al2d);
    k_gat2<<<N_NODESC / 4, 256, 0, stream>>>(off, srt, al2s, al2d, xw2, b2, out);
}

// Round 3
// 515.029 us; speedup vs baseline: 1.2300x; 1.2261x over previous
//
#include <hip/hip_runtime.h>
#include <math.h>

#define N_NODESC 100000
#define N_EDGESC 1600000
#define E_TOT    1700000   // incl. self loops
#define IN_CH    500
#define KPAD     512
#define D1 64
#define D2 24
#define D2P 32             // xw2 row padded to 128B
#define NBKT 391           // dst buckets of 256 nodes
#define CAP  5120          // fixed bucket capacity (mean 4352, sigma ~66 -> 11 sigma)
#define EPB  4096          // edges per k_part2 block
#define NPB  416           // ceil(E_TOT/EPB) partition blocks
#define WPB  32            // wprep blocks folded into k_part2

typedef __attribute__((ext_vector_type(8))) short short8;
typedef __attribute__((ext_vector_type(4))) float f32x4;

__device__ inline short f2bf(float f) {            // RTNE fp32 -> bf16
    unsigned u = __float_as_uint(f);
    u += 0x7fffu + ((u >> 16) & 1u);
    return (short)(u >> 16);
}
__device__ inline unsigned pkbf(float a, float b) {
    const unsigned ua = __float_as_uint(a) + 0x8000u;
    const unsigned ub = __float_as_uint(b) + 0x8000u;
    return __builtin_amdgcn_perm(ub, ua, 0x07060302u);  // lo16=a_bf, hi16=b_bf
}
__device__ inline float bflo(unsigned u) { return __uint_as_float(u << 16); }
__device__ inline float bfhi(unsigned u) { return __uint_as_float(u & 0xffff0000u); }

// ============ P1: partition edges into fixed-capacity dst-buckets (+ wprep) ============
// tmp[b*CAP + cursor] = src | dstLow<<17. No prior scan needed.
// Blocks >= NPB convert W1 -> bf16 transposed wT (K padded to 512).
__global__ __launch_bounds__(256) void k_part2(const int* __restrict__ ei,
                                               int* __restrict__ gcnt,   // stride 32
                                               int* __restrict__ tmp,
                                               const float* __restrict__ W1,
                                               short* __restrict__ wT) {
    const int t = threadIdx.x;
    if (blockIdx.x >= NPB) {                      // ---- folded wprep ----
        const int wb = blockIdx.x - NPB;          // 0..31
#pragma unroll
        for (int r = 0; r < 4; r++) {
            const int idx = wb * 1024 + r * 256 + t;   // < 32768
            const int n = idx >> 9, k = idx & (KPAD - 1);
            wT[idx] = (k < IN_CH) ? f2bf(W1[k * D1 + n]) : (short)0;
        }
        return;
    }
    __shared__ int hist[NBKT];
    __shared__ int lbase[NBKT];
    const int e0 = blockIdx.x * EPB;
    for (int i = t; i < NBKT; i += 256) hist[i] = 0;
    __syncthreads();
    int se[16], de[16], mo[16];
#pragma unroll
    for (int i = 0; i < 16; i++) {
        const int e = e0 + i * 256 + t;
        int s = -1, d = 0;
        if (e < E_TOT) {
            if (e < N_EDGESC) { s = ei[e]; d = ei[N_EDGESC + e]; }
            else { s = d = e - N_EDGESC; }
        }
        se[i] = s; de[i] = d;
        mo[i] = (s >= 0) ? atomicAdd(&hist[d >> 8], 1) : 0;
    }
    __syncthreads();
    for (int i = t; i < NBKT; i += 256)
        lbase[i] = hist[i] ? (i * CAP + atomicAdd(&gcnt[i * 32], hist[i])) : 0;
    __syncthreads();
#pragma unroll
    for (int i = 0; i < 16; i++) {
        if (se[i] >= 0) {
            const int b = de[i] >> 8;
            const int idx = lbase[b] + mo[i];
            if (idx < (b + 1) * CAP)              // 11-sigma guard
                tmp[idx] = se[i] | ((de[i] & 255) << 17);
        }
    }
}

// ============ P2: per-bucket CSR build (offsets + scatter), self-contained ============
__global__ __launch_bounds__(256) void k_bucket2(const int* __restrict__ gcnt,
                                                 const int* __restrict__ tmp,
                                                 int* __restrict__ off,
                                                 int* __restrict__ srt) {
    __shared__ int se[CAP];          // 20 KB bucket edge cache
    __shared__ int cnts[256];
    __shared__ int sc[256];
    __shared__ int lcur[256];
    __shared__ int red[4];
    __shared__ int sbase;
    const int b = blockIdx.x;
    const int t = threadIdx.x;
    const int cnt = min(gcnt[b * 32], CAP);

    // global base = sum of earlier buckets' counts (each thread covers <=2 entries)
    int pre = 0;
    if (t < b) pre += min(gcnt[t * 32], CAP);
    if (t + 256 < b) pre += min(gcnt[(t + 256) * 32], CAP);
#pragma unroll
    for (int m = 1; m < 64; m <<= 1) pre += __shfl_xor(pre, m, 64);
    if ((t & 63) == 0) red[t >> 6] = pre;
    cnts[t] = 0;
    __syncthreads();
    if (t == 0) sbase = red[0] + red[1] + red[2] + red[3];
    __syncthreads();
    const int base = sbase;

    // load bucket edges to LDS + per-node histogram
    for (int i = t; i < cnt; i += 256) {
        const int p = tmp[b * CAP + i];
        se[i] = p;
        atomicAdd(&cnts[p >> 17], 1);
    }
    __syncthreads();
    // inclusive scan of cnts -> sc
    sc[t] = cnts[t];
    __syncthreads();
    for (int d = 1; d < 256; d <<= 1) {
        const int u = (t >= d) ? sc[t - d] : 0;
        __syncthreads();
        sc[t] += u;
        __syncthreads();
    }
    const int excl = base + sc[t] - cnts[t];
    const int nodeBase = b << 8;
    const int nNodes = min(256, N_NODESC - nodeBase);
    if (t < nNodes) off[nodeBase + t] = excl;
    lcur[t] = excl;
    if (b == 0 && t == 0) off[N_NODESC] = E_TOT;
    __syncthreads();
    // scatter within bucket
    for (int i = t; i < cnt; i += 256) {
        const int p = se[i];
        const int pos = atomicAdd(&lcur[p >> 17], 1);
        srt[pos] = p & 0x1FFFF;
    }
}

// ============ K1: xw1 = x @ W1 via bf16 MFMA, fused al1 epilogue ============
__global__ __launch_bounds__(256) void k_gemm1(const float* __restrict__ x,
                                               const short* __restrict__ wT,
                                               const float* __restrict__ a1s,
                                               const float* __restrict__ a1d,
                                               short* __restrict__ xw1b,
                                               float* __restrict__ al1s,
                                               float* __restrict__ al1d) {
    __shared__ short xs[32 * 520];
    const int t = threadIdx.x;
    const int rowBase = blockIdx.x * 32;        // 3125 * 32 == 100000 exactly
    const int r = t >> 3, j = t & 7;
    const float* xr = x + (long)(rowBase + r) * IN_CH;
    short* xrow = xs + r * 520;
#pragma unroll
    for (int i = 0; i < 16; i++) {
        const int c = j + i * 8;                 // float4 index, 125 per row
        if (c < 125) {
            const float4 v = *(const float4*)(xr + c * 4);
            const unsigned lo = pkbf(v.x, v.y);
            const unsigned hi = pkbf(v.z, v.w);
            *(uint2*)(xrow + c * 4) = make_uint2(lo, hi);
        }
    }
    if (j < 6) *(unsigned*)(xrow + 500 + j * 2) = 0u;   // zero halfs 500..511
    __syncthreads();

    const int lane = t & 63, wv = t >> 6;
    const int m = lane & 15, kg = lane >> 4;
    f32x4 acc[2];
    acc[0] = (f32x4){0.f, 0.f, 0.f, 0.f};
    acc[1] = (f32x4){0.f, 0.f, 0.f, 0.f};
    const short* wcol = wT + (wv * 16 + m) * KPAD;
#pragma unroll
    for (int k0 = 0; k0 < KPAD; k0 += 32) {
        const short8 bf = *(const short8*)(wcol + k0 + kg * 8);
#pragma unroll
        for (int mf = 0; mf < 2; mf++) {
            const short8 af = *(const short8*)(xs + (mf * 16 + m) * 520 + k0 + kg * 8);
            acc[mf] = __builtin_amdgcn_mfma_f32_16x16x32_bf16(af, bf, acc[mf], 0, 0, 0);
        }
    }
    const int col = wv * 16 + m;
    const float as = a1s[col];
    const float ad = a1d[col];
    const int hh = wv * 2 + (m >> 3);
#pragma unroll
    for (int mf = 0; mf < 2; mf++) {
#pragma unroll
        for (int jj = 0; jj < 4; jj++) {
            const int row = rowBase + mf * 16 + kg * 4 + jj;
            const float v = acc[mf][jj];
            xw1b[(long)row * D1 + col] = f2bf(v);
            float ts = v * as, td = v * ad;
            ts += __shfl_xor(ts, 1, 64); td += __shfl_xor(td, 1, 64);
            ts += __shfl_xor(ts, 2, 64); td += __shfl_xor(td, 2, 64);
            ts += __shfl_xor(ts, 4, 64); td += __shfl_xor(td, 4, 64);
            if ((m & 7) == 0) {
                al1s[row * 8 + hh] = ts;
                al1d[row * 8 + hh] = td;
            }
        }
    }
}

// ============ K3: gather-aggregate layer 1 + fused layer-2 projection ============
__global__ __launch_bounds__(256) void k_gat1(const int* __restrict__ off,
                                              const int* __restrict__ srt_src,
                                              const float* __restrict__ al1s,
                                              const float* __restrict__ al1d,
                                              const short* __restrict__ xw1b,
                                              const float* __restrict__ b1,
                                              const float* __restrict__ W2,
                                              const float* __restrict__ a2s,
                                              const float* __restrict__ a2d,
                                              float* __restrict__ xw2,
                                              float* __restrict__ al2s,
                                              float* __restrict__ al2d) {
    __shared__ float w2s[D1 * D2];
    __shared__ float hrow[4][D1];
    const int tid = threadIdx.x;
    for (int i = tid; i < D1 * D2; i += 256) w2s[i] = W2[i];
    __syncthreads();

    const int lane = tid & 63;
    const int wid = tid >> 6;
    const int n = blockIdx.x * 4 + wid;   // N_NODESC % 4 == 0
    const int esub = lane >> 4;
    const int q = lane & 15;
    const int h = q >> 1;

    const float ald = al1d[n * 8 + h];
    const int kend = off[n + 1];

    float4 acc = make_float4(0.f, 0.f, 0.f, 0.f);
    float ssum = 0.f;
    // software-pipelined: prefetch next src index while gathering current row
    int k = off[n] + esub;
    int s = (k < kend) ? srt_src[k] : -1;
    while (s >= 0) {
        const int kn = k + 4;
        const int sn = (kn < kend) ? srt_src[kn] : -1;
        float ev = al1s[s * 8 + h] + ald;
        ev = ev > 0.f ? ev : 0.2f * ev;
        const float ex = __expf(ev);
        const uint2 v = *(const uint2*)(xw1b + (long)s * D1 + q * 4);  // 1 line/row
        acc.x += ex * bflo(v.x); acc.y += ex * bfhi(v.x);
        acc.z += ex * bflo(v.y); acc.w += ex * bfhi(v.y);
        ssum += ex;
        k = kn; s = sn;
    }
#pragma unroll
    for (int mm = 16; mm < 64; mm <<= 1) {
        acc.x += __shfl_xor(acc.x, mm, 64);
        acc.y += __shfl_xor(acc.y, mm, 64);
        acc.z += __shfl_xor(acc.z, mm, 64);
        acc.w += __shfl_xor(acc.w, mm, 64);
        ssum  += __shfl_xor(ssum,  mm, 64);
    }
    if (esub == 0) {
        const float inv = 1.0f / (ssum + 1e-16f);
        const float4 bb = *(const float4*)(b1 + q * 4);
        float4 rr;
        rr.x = acc.x * inv + bb.x; rr.x = rr.x > 0.f ? rr.x : expm1f(rr.x);
        rr.y = acc.y * inv + bb.y; rr.y = rr.y > 0.f ? rr.y : expm1f(rr.y);
        rr.z = acc.z * inv + bb.z; rr.z = rr.z > 0.f ? rr.z : expm1f(rr.z);
        rr.w = acc.w * inv + bb.w; rr.w = rr.w > 0.f ? rr.w : expm1f(rr.w);
        *(float4*)(&hrow[wid][q * 4]) = rr;   // wave-local LDS handoff
    }
    // o[j] = sum_c hrow[c]*W2[c][j]; c split over two 24-lane half-groups
    const int half = lane / 24;              // 0,1,2 (lanes 48-63 duplicate half 0)
    const int j2 = lane - half * 24;         // 0..23
    const int cb = (half == 1) ? 32 : 0;
    float o = 0.f;
#pragma unroll
    for (int c4 = 0; c4 < 8; c4++) {
        const float4 hv = *(const float4*)(&hrow[wid][cb + c4 * 4]);  // broadcast read
        const float* wr = w2s + (cb + c4 * 4) * D2 + j2;
        o += hv.x * wr[0] + hv.y * wr[D2] + hv.z * wr[2 * D2] + hv.w * wr[3 * D2];
    }
    const int src2 = (lane < 24) ? lane + 24 : lane;
    o += __shfl(o, src2, 64);                // lanes<24 hold the full 64-dot
    if (lane < 24) xw2[(long)n * D2P + lane] = o;
    const float ps = o * a2s[j2];
    const float pd = o * a2d[j2];
    const int hb = 3 * (lane & 7);
    const float s3 = __shfl(ps, hb, 64) + __shfl(ps, hb + 1, 64) + __shfl(ps, hb + 2, 64);
    const float d3 = __shfl(pd, hb, 64) + __shfl(pd, hb + 1, 64) + __shfl(pd, hb + 2, 64);
    if (lane < 8) {
        al2s[n * 8 + lane] = s3;
        al2d[n * 8 + lane] = d3;
    }
}

// ============ K5: gather-aggregate layer 2 + head-mean + softmax ============
__global__ __launch_bounds__(256) void k_gat2(const int* __restrict__ off,
                                              const int* __restrict__ srt_src,
                                              const float* __restrict__ al2s,
                                              const float* __restrict__ al2d,
                                              const float* __restrict__ xw2,
                                              const float* __restrict__ b2,
                                              float* __restrict__ out) {
    __shared__ float sm[4][24];
    const int tid = threadIdx.x;
    const int lane = tid & 63;
    const int wid = tid >> 6;
    const int n = blockIdx.x * 4 + wid;
    const int esub = lane / 24;          // 0,1,2
    const int j = lane - esub * 24;
    const int h = j / 3;

    float acc = 0.f, ssum = 0.f;
    if (esub < 2) {
        const float ald = al2d[n * 8 + h];
        const int kend = off[n + 1];
        int k = off[n] + esub;
        int s = (k < kend) ? srt_src[k] : -1;
        while (s >= 0) {
            const int kn = k + 2;
            const int sn = (kn < kend) ? srt_src[kn] : -1;
            float ev = al2s[s * 8 + h] + ald;
            ev = ev > 0.f ? ev : 0.2f * ev;
            const float ex = __expf(ev);
            acc += ex * xw2[(long)s * D2P + j];   // 1 aligned 128B line/row
            ssum += ex;
            k = kn; s = sn;
        }
    }
    acc  += __shfl_down(acc, 24, 64);
    ssum += __shfl_down(ssum, 24, 64);
    if (lane < 24) sm[wid][j] = acc / (ssum + 1e-16f);
    __syncthreads();
    float lg = 0.f;
    if (lane < 3) {
#pragma unroll
        for (int hh = 0; hh < 8; hh++) lg += sm[wid][hh * 3 + lane];
        lg = lg * 0.125f + b2[lane];
    }
    const float l0 = __shfl(lg, 0, 64);
    const float l1 = __shfl(lg, 1, 64);
    const float l2 = __shfl(lg, 2, 64);
    if (lane < 3) {
        const float m = fmaxf(l0, fmaxf(l1, l2));
        const float denom = expf(l0 - m) + expf(l1 - m) + expf(l2 - m);
        out[(long)n * 3 + lane] = expf(lg - m) / denom;
    }
}

extern "C" void kernel_launch(void* const* d_in, const int* in_sizes, int n_in,
                              void* d_out, int out_size, void* d_ws, size_t ws_size,
                              hipStream_t stream) {
    const float* x   = (const float*)d_in[0];
    const float* W1  = (const float*)d_in[1];
    const float* a1s = (const float*)d_in[2];
    const float* a1d = (const float*)d_in[3];
    const float* b1  = (const float*)d_in[4];
    const float* W2  = (const float*)d_in[5];
    const float* a2s = (const float*)d_in[6];
    const float* a2d = (const float*)d_in[7];
    const float* b2  = (const float*)d_in[8];
    const int*   ei  = (const int*)d_in[9];
    float* out = (float*)d_out;

    float* ws   = (float*)d_ws;
    float* xw2  = ws;                      // 100000*32 = 3,200,000 floats (tmp overlays)
    float* al1s = xw2  + 3200000;          //   800,000
    float* al1d = al1s + 800000;           //   800,000
    float* al2s = al1d + 800000;           //   800,000
    float* al2d = al2s + 800000;           //   800,000
    short* xw1b = (short*)(al2d + 800000); // 6,400,000 shorts (bf16)
    int* off    = (int*)(xw1b + 6400000);  //   100,004 (padded for alignment)
    int* gcnt   = off + 100004;            //   391*32 (line-padded cursors)
    int* srt    = gcnt + NBKT * 32;        // 1,700,000
    short* wT   = (short*)(srt + 1700000); //   64*512 halfs (16B aligned)
    int* tmp    = (int*)xw2;               //   391*5120 = 2,001,920 ints ( < 3.2M )

    hipMemsetAsync(gcnt, 0, (size_t)NBKT * 32 * sizeof(int), stream);

    k_part2<<<NPB + WPB, 256, 0, stream>>>(ei, gcnt, tmp, W1, wT);
    k_bucket2<<<NBKT, 256, 0, stream>>>(gcnt, tmp, off, srt);
    k_gemm1<<<N_NODESC / 32, 256, 0, stream>>>(x, wT, a1s, a1d, xw1b, al1s, al1d);
    k_gat1<<<N_NODESC / 4, 256, 0, stream>>>(off, srt, al1s, al1d, xw1b, b1,
                                             W2, a2s, a2d, xw2, al2s, al2d);
    k_gat2<<<N_NODESC / 4, 256, 0, stream>>>(off, srt, al2s, al2d, xw2, b2, out);
}

// Round 4
// 483.378 us; speedup vs baseline: 1.3105x; 1.0655x over previous
//
#include <hip/hip_runtime.h>
#include <math.h>

#define N_NODESC 100000
#define N_EDGESC 1600000
#define E_TOT    1700000   // incl. self loops
#define IN_CH    500
#define KPAD     512
#define D1 64
#define D2 24
#define D2P 32             // xw2 row: 8 heads x (3 classes + 1 pad) = 128B
#define NBKT 391           // dst buckets of 256 nodes
#define CAP  5120          // fixed bucket capacity (mean 4352, sigma ~66 -> 11 sigma)
#define EPB  4096          // edges per k_part2 block
#define NPB  416           // ceil(E_TOT/EPB) partition blocks
#define WPB  32            // wprep blocks folded into k_part2

typedef __attribute__((ext_vector_type(8))) short short8;
typedef __attribute__((ext_vector_type(4))) float f32x4;

__device__ inline short f2bf(float f) {            // RTNE fp32 -> bf16
    unsigned u = __float_as_uint(f);
    u += 0x7fffu + ((u >> 16) & 1u);
    return (short)(u >> 16);
}
__device__ inline unsigned pkbf(float a, float b) {
    const unsigned ua = __float_as_uint(a) + 0x8000u;
    const unsigned ub = __float_as_uint(b) + 0x8000u;
    return __builtin_amdgcn_perm(ub, ua, 0x07060302u);  // lo16=a_bf, hi16=b_bf
}
__device__ inline float bflo(unsigned u) { return __uint_as_float(u << 16); }
__device__ inline float bfhi(unsigned u) { return __uint_as_float(u & 0xffff0000u); }

// ============ P1: partition edges into fixed-capacity dst-buckets (+ wprep) ============
__global__ __launch_bounds__(256) void k_part2(const int* __restrict__ ei,
                                               int* __restrict__ gcnt,   // stride 32
                                               int* __restrict__ tmp,
                                               const float* __restrict__ W1,
                                               short* __restrict__ wT) {
    const int t = threadIdx.x;
    if (blockIdx.x >= NPB) {                      // ---- folded wprep ----
        const int wb = blockIdx.x - NPB;          // 0..31
#pragma unroll
        for (int r = 0; r < 4; r++) {
            const int idx = wb * 1024 + r * 256 + t;   // < 32768
            const int n = idx >> 9, k = idx & (KPAD - 1);
            wT[idx] = (k < IN_CH) ? f2bf(W1[k * D1 + n]) : (short)0;
        }
        return;
    }
    __shared__ int hist[NBKT];
    __shared__ int lbase[NBKT];
    const int e0 = blockIdx.x * EPB;
    for (int i = t; i < NBKT; i += 256) hist[i] = 0;
    __syncthreads();
    int se[16], de[16], mo[16];
#pragma unroll
    for (int i = 0; i < 16; i++) {
        const int e = e0 + i * 256 + t;
        int s = -1, d = 0;
        if (e < E_TOT) {
            if (e < N_EDGESC) { s = ei[e]; d = ei[N_EDGESC + e]; }
            else { s = d = e - N_EDGESC; }
        }
        se[i] = s; de[i] = d;
        mo[i] = (s >= 0) ? atomicAdd(&hist[d >> 8], 1) : 0;
    }
    __syncthreads();
    for (int i = t; i < NBKT; i += 256)
        lbase[i] = hist[i] ? (i * CAP + atomicAdd(&gcnt[i * 32], hist[i])) : 0;
    __syncthreads();
#pragma unroll
    for (int i = 0; i < 16; i++) {
        if (se[i] >= 0) {
            const int b = de[i] >> 8;
            const int idx = lbase[b] + mo[i];
            if (idx < (b + 1) * CAP)              // 11-sigma guard
                tmp[idx] = se[i] | ((de[i] & 255) << 17);
        }
    }
}

// ============ P2: per-bucket CSR build (offsets + scatter), self-contained ============
__global__ __launch_bounds__(256) void k_bucket2(const int* __restrict__ gcnt,
                                                 const int* __restrict__ tmp,
                                                 int* __restrict__ off,
                                                 int* __restrict__ srt) {
    __shared__ int se[CAP];          // 20 KB bucket edge cache
    __shared__ int cnts[256];
    __shared__ int sc[256];
    __shared__ int lcur[256];
    __shared__ int red[4];
    __shared__ int sbase;
    const int b = blockIdx.x;
    const int t = threadIdx.x;
    const int cnt = min(gcnt[b * 32], CAP);

    int pre = 0;
    if (t < b) pre += min(gcnt[t * 32], CAP);
    if (t + 256 < b) pre += min(gcnt[(t + 256) * 32], CAP);
#pragma unroll
    for (int m = 1; m < 64; m <<= 1) pre += __shfl_xor(pre, m, 64);
    if ((t & 63) == 0) red[t >> 6] = pre;
    cnts[t] = 0;
    __syncthreads();
    if (t == 0) sbase = red[0] + red[1] + red[2] + red[3];
    __syncthreads();
    const int base = sbase;

    for (int i = t; i < cnt; i += 256) {
        const int p = tmp[b * CAP + i];
        se[i] = p;
        atomicAdd(&cnts[p >> 17], 1);
    }
    __syncthreads();
    sc[t] = cnts[t];
    __syncthreads();
    for (int d = 1; d < 256; d <<= 1) {
        const int u = (t >= d) ? sc[t - d] : 0;
        __syncthreads();
        sc[t] += u;
        __syncthreads();
    }
    const int excl = base + sc[t] - cnts[t];
    const int nodeBase = b << 8;
    const int nNodes = min(256, N_NODESC - nodeBase);
    if (t < nNodes) off[nodeBase + t] = excl;
    lcur[t] = excl;
    if (b == 0 && t == 0) off[N_NODESC] = E_TOT;
    __syncthreads();
    for (int i = t; i < cnt; i += 256) {
        const int p = se[i];
        const int pos = atomicAdd(&lcur[p >> 17], 1);
        srt[pos] = p & 0x1FFFF;
    }
}

// ============ K1: xw1 = x @ W1 via bf16 MFMA, fused al1 epilogue ============
__global__ __launch_bounds__(256) void k_gemm1(const float* __restrict__ x,
                                               const short* __restrict__ wT,
                                               const float* __restrict__ a1s,
                                               const float* __restrict__ a1d,
                                               short* __restrict__ xw1b,
                                               float* __restrict__ al1s,
                                               float* __restrict__ al1d) {
    __shared__ short xs[32 * 520];
    const int t = threadIdx.x;
    const int rowBase = blockIdx.x * 32;        // 3125 * 32 == 100000 exactly
    const int r = t >> 3, j = t & 7;
    const float* xr = x + (long)(rowBase + r) * IN_CH;
    short* xrow = xs + r * 520;
#pragma unroll
    for (int i = 0; i < 16; i++) {
        const int c = j + i * 8;                 // float4 index, 125 per row
        if (c < 125) {
            const float4 v = *(const float4*)(xr + c * 4);
            const unsigned lo = pkbf(v.x, v.y);
            const unsigned hi = pkbf(v.z, v.w);
            *(uint2*)(xrow + c * 4) = make_uint2(lo, hi);
        }
    }
    if (j < 6) *(unsigned*)(xrow + 500 + j * 2) = 0u;   // zero halfs 500..511
    __syncthreads();

    const int lane = t & 63, wv = t >> 6;
    const int m = lane & 15, kg = lane >> 4;
    f32x4 acc[2];
    acc[0] = (f32x4){0.f, 0.f, 0.f, 0.f};
    acc[1] = (f32x4){0.f, 0.f, 0.f, 0.f};
    const short* wcol = wT + (wv * 16 + m) * KPAD;
#pragma unroll
    for (int k0 = 0; k0 < KPAD; k0 += 32) {
        const short8 bf = *(const short8*)(wcol + k0 + kg * 8);
#pragma unroll
        for (int mf = 0; mf < 2; mf++) {
            const short8 af = *(const short8*)(xs + (mf * 16 + m) * 520 + k0 + kg * 8);
            acc[mf] = __builtin_amdgcn_mfma_f32_16x16x32_bf16(af, bf, acc[mf], 0, 0, 0);
        }
    }
    const int col = wv * 16 + m;
    const float as = a1s[col];
    const float ad = a1d[col];
    const int hh = wv * 2 + (m >> 3);
#pragma unroll
    for (int mf = 0; mf < 2; mf++) {
#pragma unroll
        for (int jj = 0; jj < 4; jj++) {
            const int row = rowBase + mf * 16 + kg * 4 + jj;
            const float v = acc[mf][jj];
            xw1b[(long)row * D1 + col] = f2bf(v);
            float ts = v * as, td = v * ad;
            ts += __shfl_xor(ts, 1, 64); td += __shfl_xor(td, 1, 64);
            ts += __shfl_xor(ts, 2, 64); td += __shfl_xor(td, 2, 64);
            ts += __shfl_xor(ts, 4, 64); td += __shfl_xor(td, 4, 64);
            if ((m & 7) == 0) {
                al1s[row * 8 + hh] = ts;
                al1d[row * 8 + hh] = td;
            }
        }
    }
}

// ============ K3: gather-aggregate layer 1 + fused layer-2 projection ============
// Lane = (edge-slot e8, head hd). 8 gather streams/wave, one expf per (edge,head),
// one dwordx4 per lane covers the full 128B xw1b row across 8 lanes.
__global__ __launch_bounds__(256) void k_gat1(const int* __restrict__ off,
                                              const int* __restrict__ srt_src,
                                              const float* __restrict__ al1s,
                                              const float* __restrict__ al1d,
                                              const short* __restrict__ xw1b,
                                              const float* __restrict__ b1,
                                              const float* __restrict__ W2,
                                              const float* __restrict__ a2s,
                                              const float* __restrict__ a2d,
                                              float* __restrict__ xw2,
                                              float* __restrict__ al2s,
                                              float* __restrict__ al2d) {
    __shared__ float w2s[D1 * D2];
    __shared__ float hrow[4][D1];
    const int tid = threadIdx.x;
    for (int i = tid; i < D1 * D2; i += 256) w2s[i] = W2[i];
    __syncthreads();

    const int lane = tid & 63;
    const int wid = tid >> 6;
    const int n = blockIdx.x * 4 + wid;   // N_NODESC % 4 == 0
    const int e8 = lane >> 3;             // edge slot 0..7
    const int hd = lane & 7;              // head 0..7 (= dim octet)

    const float ald = al1d[n * 8 + hd];
    const int kend = off[n + 1];

    float4 a0 = make_float4(0.f, 0.f, 0.f, 0.f);
    float4 a1 = make_float4(0.f, 0.f, 0.f, 0.f);
    float ssum = 0.f;
    int k = off[n] + e8;
    int s = (k < kend) ? srt_src[k] : -1;
    while (s >= 0) {
        const int kn = k + 8;
        const int sn = (kn < kend) ? srt_src[kn] : -1;
        float ev = al1s[s * 8 + hd] + ald;
        ev = ev > 0.f ? ev : 0.2f * ev;
        const float ex = __expf(ev);
        const uint4 v = *(const uint4*)(xw1b + (long)s * D1 + hd * 8);  // 16B; 8 lanes = row
        a0.x += ex * bflo(v.x); a0.y += ex * bfhi(v.x);
        a0.z += ex * bflo(v.y); a0.w += ex * bfhi(v.y);
        a1.x += ex * bflo(v.z); a1.y += ex * bfhi(v.z);
        a1.z += ex * bflo(v.w); a1.w += ex * bfhi(v.w);
        ssum += ex;
        k = kn; s = sn;
    }
    // reduce across the 8 edge slots (lane bits 3,4,5)
#pragma unroll
    for (int mm = 8; mm < 64; mm <<= 1) {
        a0.x += __shfl_xor(a0.x, mm, 64); a0.y += __shfl_xor(a0.y, mm, 64);
        a0.z += __shfl_xor(a0.z, mm, 64); a0.w += __shfl_xor(a0.w, mm, 64);
        a1.x += __shfl_xor(a1.x, mm, 64); a1.y += __shfl_xor(a1.y, mm, 64);
        a1.z += __shfl_xor(a1.z, mm, 64); a1.w += __shfl_xor(a1.w, mm, 64);
        ssum  += __shfl_xor(ssum,  mm, 64);
    }
    const float inv = 1.0f / (ssum + 1e-16f);
    const float4 bb0 = *(const float4*)(b1 + hd * 8);
    const float4 bb1 = *(const float4*)(b1 + hd * 8 + 4);
    float4 r0, r1;
    r0.x = a0.x * inv + bb0.x; r0.x = r0.x > 0.f ? r0.x : expm1f(r0.x);
    r0.y = a0.y * inv + bb0.y; r0.y = r0.y > 0.f ? r0.y : expm1f(r0.y);
    r0.z = a0.z * inv + bb0.z; r0.z = r0.z > 0.f ? r0.z : expm1f(r0.z);
    r0.w = a0.w * inv + bb0.w; r0.w = r0.w > 0.f ? r0.w : expm1f(r0.w);
    r1.x = a1.x * inv + bb1.x; r1.x = r1.x > 0.f ? r1.x : expm1f(r1.x);
    r1.y = a1.y * inv + bb1.y; r1.y = r1.y > 0.f ? r1.y : expm1f(r1.y);
    r1.z = a1.z * inv + bb1.z; r1.z = r1.z > 0.f ? r1.z : expm1f(r1.z);
    r1.w = a1.w * inv + bb1.w; r1.w = r1.w > 0.f ? r1.w : expm1f(r1.w);
    if (e8 == 0) {                          // lanes 0..7: write dims hd*8..hd*8+7
        *(float4*)(&hrow[wid][hd * 8])     = r0;
        *(float4*)(&hrow[wid][hd * 8 + 4]) = r1;
    }
    // same-wave LDS handoff (no barrier needed); layer-2 projection
    const int half = lane / 24;              // 0,1,2 (lanes 48-63 duplicate half 0)
    const int j2 = lane - half * 24;         // 0..23
    const int cb = (half == 1) ? 32 : 0;
    float o = 0.f;
#pragma unroll
    for (int c4 = 0; c4 < 8; c4++) {
        const float4 hv = *(const float4*)(&hrow[wid][cb + c4 * 4]);  // broadcast read
        const float* wr = w2s + (cb + c4 * 4) * D2 + j2;
        o += hv.x * wr[0] + hv.y * wr[D2] + hv.z * wr[2 * D2] + hv.w * wr[3 * D2];
    }
    const int src2 = (lane < 24) ? lane + 24 : lane;
    o += __shfl(o, src2, 64);                // lanes<24 hold the full 64-dot
    if (lane < 24) {                         // head-padded xw2 layout: [8][4]
        const int h3 = j2 / 3;
        xw2[(long)n * D2P + h3 * 4 + (j2 - 3 * h3)] = o;
    }
    const float ps = o * a2s[j2];
    const float pd = o * a2d[j2];
    const int hb = 3 * (lane & 7);
    const float s3 = __shfl(ps, hb, 64) + __shfl(ps, hb + 1, 64) + __shfl(ps, hb + 2, 64);
    const float d3 = __shfl(pd, hb, 64) + __shfl(pd, hb + 1, 64) + __shfl(pd, hb + 2, 64);
    if (lane < 8) {
        al2s[n * 8 + lane] = s3;
        al2d[n * 8 + lane] = d3;
    }
}

// ============ K5: gather-aggregate layer 2 + head-mean + softmax ============
// Lane = (edge-slot e8, head hd). All 64 lanes active, 8 gather streams/wave,
// one expf per (edge,head); no LDS, no barrier.
__global__ __launch_bounds__(256) void k_gat2(const int* __restrict__ off,
                                              const int* __restrict__ srt_src,
                                              const float* __restrict__ al2s,
                                              const float* __restrict__ al2d,
                                              const float* __restrict__ xw2,
                                              const float* __restrict__ b2,
                                              float* __restrict__ out) {
    const int tid = threadIdx.x;
    const int lane = tid & 63;
    const int wid = tid >> 6;
    const int n = blockIdx.x * 4 + wid;
    const int e8 = lane >> 3;
    const int hd = lane & 7;

    const float ald = al2d[n * 8 + hd];
    const int kend = off[n + 1];

    float ax = 0.f, ay = 0.f, az = 0.f, ssum = 0.f;
    int k = off[n] + e8;
    int s = (k < kend) ? srt_src[k] : -1;
    while (s >= 0) {
        const int kn = k + 8;
        const int sn = (kn < kend) ? srt_src[kn] : -1;
        float ev = al2s[s * 8 + hd] + ald;
        ev = ev > 0.f ? ev : 0.2f * ev;
        const float ex = __expf(ev);
        const float4 v = *(const float4*)(xw2 + (long)s * D2P + hd * 4);  // head's 3 classes
        ax += ex * v.x; ay += ex * v.y; az += ex * v.z;
        ssum += ex;
        k = kn; s = sn;
    }
    // reduce across 8 edge slots (bits 3,4,5)
#pragma unroll
    for (int mm = 8; mm < 64; mm <<= 1) {
        ax += __shfl_xor(ax, mm, 64);
        ay += __shfl_xor(ay, mm, 64);
        az += __shfl_xor(az, mm, 64);
        ssum += __shfl_xor(ssum, mm, 64);
    }
    const float inv = 1.0f / (ssum + 1e-16f);
    float mx = ax * inv, my = ay * inv, mz = az * inv;   // this head's alpha-mean
    // head mean: reduce over head bits 0,1,2
#pragma unroll
    for (int mm = 1; mm < 8; mm <<= 1) {
        mx += __shfl_xor(mx, mm, 64);
        my += __shfl_xor(my, mm, 64);
        mz += __shfl_xor(mz, mm, 64);
    }
    const float l0 = mx * 0.125f + b2[0];
    const float l1 = my * 0.125f + b2[1];
    const float l2 = mz * 0.125f + b2[2];
    const float mmax = fmaxf(l0, fmaxf(l1, l2));
    const float ee0 = expf(l0 - mmax), ee1 = expf(l1 - mmax), ee2 = expf(l2 - mmax);
    const float dinv = 1.0f / (ee0 + ee1 + ee2);
    if (lane < 3) {
        const float p = (lane == 0) ? ee0 : (lane == 1) ? ee1 : ee2;
        out[(long)n * 3 + lane] = p * dinv;
    }
}

extern "C" void kernel_launch(void* const* d_in, const int* in_sizes, int n_in,
                              void* d_out, int out_size, void* d_ws, size_t ws_size,
                              hipStream_t stream) {
    const float* x   = (const float*)d_in[0];
    const float* W1  = (const float*)d_in[1];
    const float* a1s = (const float*)d_in[2];
    const float* a1d = (const float*)d_in[3];
    const float* b1  = (const float*)d_in[4];
    const float* W2  = (const float*)d_in[5];
    const float* a2s = (const float*)d_in[6];
    const float* a2d = (const float*)d_in[7];
    const float* b2  = (const float*)d_in[8];
    const int*   ei  = (const int*)d_in[9];
    float* out = (float*)d_out;

    float* ws   = (float*)d_ws;
    float* xw2  = ws;                      // 100000*32 = 3,200,000 floats (tmp overlays)
    float* al1s = xw2  + 3200000;          //   800,000
    float* al1d = al1s + 800000;           //   800,000
    float* al2s = al1d + 800000;           //   800,000
    float* al2d = al2s + 800000;           //   800,000
    short* xw1b = (short*)(al2d + 800000); // 6,400,000 shorts (bf16)
    int* off    = (int*)(xw1b + 6400000);  //   100,004 (padded for alignment)
    int* gcnt   = off + 100004;            //   391*32 (line-padded cursors)
    int* srt    = gcnt + NBKT * 32;        // 1,700,000
    short* wT   = (short*)(srt + 1700000); //   64*512 halfs (16B aligned)
    int* tmp    = (int*)xw2;               //   391*5120 = 2,001,920 ints ( < 3.2M )

    hipMemsetAsync(gcnt, 0, (size_t)NBKT * 32 * sizeof(int), stream);

    k_part2<<<NPB + WPB, 256, 0, stream>>>(ei, gcnt, tmp, W1, wT);
    k_bucket2<<<NBKT, 256, 0, stream>>>(gcnt, tmp, off, srt);
    k_gemm1<<<N_NODESC / 32, 256, 0, stream>>>(x, wT, a1s, a1d, xw1b, al1s, al1d);
    k_gat1<<<N_NODESC / 4, 256, 0, stream>>>(off, srt, al1s, al1d, xw1b, b1,
                                             W2, a2s, a2d, xw2, al2s, al2d);
    k_gat2<<<N_NODESC / 4, 256, 0, stream>>>(off, srt, al2s, al2d, xw2, b2, out);
}

// Round 5
// 466.958 us; speedup vs baseline: 1.3566x; 1.0352x over previous
//
#include <hip/hip_runtime.h>
#include <math.h>

#define N_NODESC 100000
#define N_EDGESC 1600000
#define E_TOT    1700000   // incl. self loops
#define IN_CH    500
#define KPAD     512
#define D1 64
#define D2 24
#define D2P 32             // xw2 row: 8 heads x (3 classes + src-logit) = 128B
#define NBKT 391           // dst buckets of 256 nodes
#define CAP  5120          // fixed bucket capacity (mean 4352, sigma ~66 -> 11 sigma)
#define EPB  4096          // edges per partition block
#define NPB  416           // ceil(E_TOT/EPB) partition blocks
#define GEMB 3125          // gemm blocks (100000/32)

typedef __attribute__((ext_vector_type(8))) short short8;
typedef __attribute__((ext_vector_type(4))) float f32x4;

__device__ inline short f2bf(float f) {            // RTNE fp32 -> bf16
    unsigned u = __float_as_uint(f);
    u += 0x7fffu + ((u >> 16) & 1u);
    return (short)(u >> 16);
}
__device__ inline unsigned pkbf(float a, float b) {
    const unsigned ua = __float_as_uint(a) + 0x8000u;
    const unsigned ub = __float_as_uint(b) + 0x8000u;
    return __builtin_amdgcn_perm(ub, ua, 0x07060302u);  // lo16=a_bf, hi16=b_bf
}
__device__ inline float bflo(unsigned u) { return __uint_as_float(u << 16); }
__device__ inline float bfhi(unsigned u) { return __uint_as_float(u & 0xffff0000u); }

// ============ K0: zero bucket cursors + W1 -> bf16 transposed (replaces memset+wprep) ============
__global__ __launch_bounds__(256) void k_init(int* __restrict__ gcnt,
                                              const float* __restrict__ W1,
                                              short* __restrict__ wT) {
    const int tid = blockIdx.x * 256 + threadIdx.x;     // 64 blocks -> 16384 threads
    for (int i = tid; i < D1 * KPAD; i += 16384) {
        const int n = i >> 9, k = i & (KPAD - 1);
        wT[i] = (k < IN_CH) ? f2bf(W1[k * D1 + n]) : (short)0;
    }
    for (int i = tid; i < NBKT * 32; i += 16384) gcnt[i] = 0;
}

// ============ K1 (fused): edge partition [blocks 0..NPB) + gemm1 [blocks NPB..) ============
// Partition: atomic/latency-bound, 416 blocks. Gemm: MFMA-bound, 3125 blocks.
// Independent inputs/outputs -> safe concurrency, complementary pipes.
__global__ __launch_bounds__(256) void k_pg(const int* __restrict__ ei,
                                            int* __restrict__ gcnt,   // stride 32
                                            int* __restrict__ tmp,
                                            const float* __restrict__ x,
                                            const short* __restrict__ wT,
                                            const float* __restrict__ a1s,
                                            const float* __restrict__ a1d,
                                            short* __restrict__ xw1b,
                                            float* __restrict__ al1s,
                                            float* __restrict__ al1d) {
    __shared__ short xs[32 * 520];                     // 33.3 KB; partition path aliases it
    const int t = threadIdx.x;

    if (blockIdx.x < NPB) {                            // ---- partition path ----
        int* hist  = (int*)xs;                         // NBKT ints
        int* lbase = hist + NBKT;                      // NBKT ints
        const int e0 = blockIdx.x * EPB;
        for (int i = t; i < NBKT; i += 256) hist[i] = 0;
        __syncthreads();
        int se[16], de[16], mo[16];
#pragma unroll
        for (int i = 0; i < 16; i++) {
            const int e = e0 + i * 256 + t;
            int s = -1, d = 0;
            if (e < E_TOT) {
                if (e < N_EDGESC) { s = ei[e]; d = ei[N_EDGESC + e]; }
                else { s = d = e - N_EDGESC; }
            }
            se[i] = s; de[i] = d;
            mo[i] = (s >= 0) ? atomicAdd(&hist[d >> 8], 1) : 0;
        }
        __syncthreads();
        for (int i = t; i < NBKT; i += 256)
            lbase[i] = hist[i] ? (i * CAP + atomicAdd(&gcnt[i * 32], hist[i])) : 0;
        __syncthreads();
#pragma unroll
        for (int i = 0; i < 16; i++) {
            if (se[i] >= 0) {
                const int b = de[i] >> 8;
                const int idx = lbase[b] + mo[i];
                if (idx < (b + 1) * CAP)               // 11-sigma guard
                    tmp[idx] = se[i] | ((de[i] & 255) << 17);
            }
        }
        return;
    }

    // ---- gemm path: xw1 = x @ W1 (bf16 MFMA), fused al1 epilogue ----
    const int rowBase = (blockIdx.x - NPB) * 32;       // 3125 * 32 == 100000
    const int r = t >> 3, j = t & 7;
    const float* xr = x + (long)(rowBase + r) * IN_CH;
    short* xrow = xs + r * 520;
#pragma unroll
    for (int i = 0; i < 16; i++) {
        const int c = j + i * 8;                       // float4 index, 125 per row
        if (c < 125) {
            const float4 v = *(const float4*)(xr + c * 4);
            const unsigned lo = pkbf(v.x, v.y);
            const unsigned hi = pkbf(v.z, v.w);
            *(uint2*)(xrow + c * 4) = make_uint2(lo, hi);
        }
    }
    if (j < 6) *(unsigned*)(xrow + 500 + j * 2) = 0u;  // zero halfs 500..511
    __syncthreads();

    const int lane = t & 63, wv = t >> 6;
    const int m = lane & 15, kg = lane >> 4;
    f32x4 acc[2];
    acc[0] = (f32x4){0.f, 0.f, 0.f, 0.f};
    acc[1] = (f32x4){0.f, 0.f, 0.f, 0.f};
    const short* wcol = wT + (wv * 16 + m) * KPAD;
#pragma unroll
    for (int k0 = 0; k0 < KPAD; k0 += 32) {
        const short8 bf = *(const short8*)(wcol + k0 + kg * 8);
#pragma unroll
        for (int mf = 0; mf < 2; mf++) {
            const short8 af = *(const short8*)(xs + (mf * 16 + m) * 520 + k0 + kg * 8);
            acc[mf] = __builtin_amdgcn_mfma_f32_16x16x32_bf16(af, bf, acc[mf], 0, 0, 0);
        }
    }
    const int col = wv * 16 + m;
    const float as = a1s[col];
    const float ad = a1d[col];
    const int hh = wv * 2 + (m >> 3);
#pragma unroll
    for (int mf = 0; mf < 2; mf++) {
#pragma unroll
        for (int jj = 0; jj < 4; jj++) {
            const int row = rowBase + mf * 16 + kg * 4 + jj;
            const float v = acc[mf][jj];
            xw1b[(long)row * D1 + col] = f2bf(v);
            float ts = v * as, td = v * ad;
            ts += __shfl_xor(ts, 1, 64); td += __shfl_xor(td, 1, 64);
            ts += __shfl_xor(ts, 2, 64); td += __shfl_xor(td, 2, 64);
            ts += __shfl_xor(ts, 4, 64); td += __shfl_xor(td, 4, 64);
            if ((m & 7) == 0) {
                al1s[row * 8 + hh] = ts;
                al1d[row * 8 + hh] = td;
            }
        }
    }
}

// ============ K2: per-bucket CSR build (offsets + scatter), 512 threads ============
__global__ __launch_bounds__(512) void k_bucket2(const int* __restrict__ gcnt,
                                                 const int* __restrict__ tmp,
                                                 int* __restrict__ off,
                                                 int* __restrict__ srt) {
    __shared__ int se[CAP];          // 20 KB bucket edge cache
    __shared__ int cnts[256];
    __shared__ int sc[256];
    __shared__ int lcur[256];
    __shared__ int red[8];
    __shared__ int sbase;
    const int b = blockIdx.x;
    const int t = threadIdx.x;
    const int cnt = min(gcnt[b * 32], CAP);

    int pre = (t < b) ? min(gcnt[t * 32], CAP) : 0;    // 512 threads cover all 391 buckets
#pragma unroll
    for (int m = 1; m < 64; m <<= 1) pre += __shfl_xor(pre, m, 64);
    if ((t & 63) == 0) red[t >> 6] = pre;
    if (t < 256) cnts[t] = 0;
    __syncthreads();
    if (t == 0) {
        int sb = 0;
#pragma unroll
        for (int i = 0; i < 8; i++) sb += red[i];
        sbase = sb;
    }
    __syncthreads();
    const int base = sbase;

    for (int i = t; i < cnt; i += 512) {
        const int p = tmp[b * CAP + i];
        se[i] = p;
        atomicAdd(&cnts[p >> 17], 1);
    }
    __syncthreads();
    if (t < 256) sc[t] = cnts[t];
    __syncthreads();
    for (int d = 1; d < 256; d <<= 1) {
        const int u = (t >= d && t < 256) ? sc[t - d] : 0;
        __syncthreads();
        if (t < 256) sc[t] += u;
        __syncthreads();
    }
    const int nodeBase = b << 8;
    const int nNodes = min(256, N_NODESC - nodeBase);
    if (t < 256) {
        const int excl = base + sc[t] - cnts[t];
        if (t < nNodes) off[nodeBase + t] = excl;
        lcur[t] = excl;
    }
    if (b == 0 && t == 0) off[N_NODESC] = E_TOT;
    __syncthreads();
    for (int i = t; i < cnt; i += 512) {
        const int p = se[i];
        const int pos = atomicAdd(&lcur[p >> 17], 1);
        srt[pos] = p & 0x1FFFF;
    }
}

// ============ K3: gather-aggregate layer 1 + fused layer-2 projection ============
// Lane = (edge-slot e8, head hd). Fully software-pipelined (index+logit+feature
// prefetched one iteration ahead). Layer-2 src-logit packed into xw2 pad slot.
__global__ __launch_bounds__(256) void k_gat1(const int* __restrict__ off,
                                              const int* __restrict__ srt_src,
                                              const float* __restrict__ al1s,
                                              const float* __restrict__ al1d,
                                              const short* __restrict__ xw1b,
                                              const float* __restrict__ b1,
                                              const float* __restrict__ W2,
                                              const float* __restrict__ a2s,
                                              const float* __restrict__ a2d,
                                              float* __restrict__ xw2,
                                              float* __restrict__ al2d) {
    __shared__ float w2s[D1 * D2];
    __shared__ float hrow[4][D1];
    const int tid = threadIdx.x;
    for (int i = tid; i < D1 * D2; i += 256) w2s[i] = W2[i];
    __syncthreads();

    const int lane = tid & 63;
    const int wid = tid >> 6;
    const int n = blockIdx.x * 4 + wid;   // N_NODESC % 4 == 0
    const int e8 = lane >> 3;             // edge slot 0..7
    const int hd = lane & 7;              // head 0..7 (= dim octet)

    const float ald = al1d[n * 8 + hd];
    const int kend = off[n + 1];

    float4 a0 = make_float4(0.f, 0.f, 0.f, 0.f);
    float4 a1 = make_float4(0.f, 0.f, 0.f, 0.f);
    float ssum = 0.f;
    int k = off[n] + e8;
    int s = (k < kend) ? srt_src[k] : -1;
    float al = 0.f;
    uint4 v = make_uint4(0u, 0u, 0u, 0u);
    if (s >= 0) {
        al = al1s[s * 8 + hd];
        v = *(const uint4*)(xw1b + (long)s * D1 + hd * 8);
    }
    while (s >= 0) {
        const int kn = k + 8;
        const int sn = (kn < kend) ? srt_src[kn] : -1;
        float aln = 0.f;
        uint4 vn = v;
        if (sn >= 0) {                               // prefetch next edge's data
            aln = al1s[sn * 8 + hd];
            vn = *(const uint4*)(xw1b + (long)sn * D1 + hd * 8);
        }
        float ev = al + ald;
        ev = ev > 0.f ? ev : 0.2f * ev;
        const float ex = __expf(ev);
        a0.x += ex * bflo(v.x); a0.y += ex * bfhi(v.x);
        a0.z += ex * bflo(v.y); a0.w += ex * bfhi(v.y);
        a1.x += ex * bflo(v.z); a1.y += ex * bfhi(v.z);
        a1.z += ex * bflo(v.w); a1.w += ex * bfhi(v.w);
        ssum += ex;
        k = kn; s = sn; al = aln; v = vn;
    }
    // reduce across the 8 edge slots (lane bits 3,4,5)
#pragma unroll
    for (int mm = 8; mm < 64; mm <<= 1) {
        a0.x += __shfl_xor(a0.x, mm, 64); a0.y += __shfl_xor(a0.y, mm, 64);
        a0.z += __shfl_xor(a0.z, mm, 64); a0.w += __shfl_xor(a0.w, mm, 64);
        a1.x += __shfl_xor(a1.x, mm, 64); a1.y += __shfl_xor(a1.y, mm, 64);
        a1.z += __shfl_xor(a1.z, mm, 64); a1.w += __shfl_xor(a1.w, mm, 64);
        ssum  += __shfl_xor(ssum,  mm, 64);
    }
    const float inv = 1.0f / (ssum + 1e-16f);
    const float4 bb0 = *(const float4*)(b1 + hd * 8);
    const float4 bb1 = *(const float4*)(b1 + hd * 8 + 4);
    float4 r0, r1;
    r0.x = a0.x * inv + bb0.x; r0.x = r0.x > 0.f ? r0.x : expm1f(r0.x);
    r0.y = a0.y * inv + bb0.y; r0.y = r0.y > 0.f ? r0.y : expm1f(r0.y);
    r0.z = a0.z * inv + bb0.z; r0.z = r0.z > 0.f ? r0.z : expm1f(r0.z);
    r0.w = a0.w * inv + bb0.w; r0.w = r0.w > 0.f ? r0.w : expm1f(r0.w);
    r1.x = a1.x * inv + bb1.x; r1.x = r1.x > 0.f ? r1.x : expm1f(r1.x);
    r1.y = a1.y * inv + bb1.y; r1.y = r1.y > 0.f ? r1.y : expm1f(r1.y);
    r1.z = a1.z * inv + bb1.z; r1.z = r1.z > 0.f ? r1.z : expm1f(r1.z);
    r1.w = a1.w * inv + bb1.w; r1.w = r1.w > 0.f ? r1.w : expm1f(r1.w);
    if (e8 == 0) {                          // lanes 0..7: write dims hd*8..hd*8+7
        *(float4*)(&hrow[wid][hd * 8])     = r0;
        *(float4*)(&hrow[wid][hd * 8 + 4]) = r1;
    }
    // same-wave LDS handoff (no barrier needed); layer-2 projection
    const int half = lane / 24;              // 0,1,2 (lanes 48-63 duplicate half 0)
    const int j2 = lane - half * 24;         // 0..23
    const int cb = (half == 1) ? 32 : 0;
    float o = 0.f;
#pragma unroll
    for (int c4 = 0; c4 < 8; c4++) {
        const float4 hv = *(const float4*)(&hrow[wid][cb + c4 * 4]);  // broadcast read
        const float* wr = w2s + (cb + c4 * 4) * D2 + j2;
        o += hv.x * wr[0] + hv.y * wr[D2] + hv.z * wr[2 * D2] + hv.w * wr[3 * D2];
    }
    const int src2 = (lane < 24) ? lane + 24 : lane;
    o += __shfl(o, src2, 64);                // lanes<24 hold the full 64-dot
    if (lane < 24) {                         // head-padded xw2 layout: [8][4]
        const int h3 = j2 / 3;
        xw2[(long)n * D2P + h3 * 4 + (j2 - 3 * h3)] = o;
    }
    const float ps = o * a2s[j2];
    const float pd = o * a2d[j2];
    const int hb = 3 * (lane & 7);
    const float s3 = __shfl(ps, hb, 64) + __shfl(ps, hb + 1, 64) + __shfl(ps, hb + 2, 64);
    const float d3 = __shfl(pd, hb, 64) + __shfl(pd, hb + 1, 64) + __shfl(pd, hb + 2, 64);
    if (lane < 8) {
        xw2[(long)n * D2P + lane * 4 + 3] = s3;   // src-logit in pad slot
        al2d[n * 8 + lane] = d3;
    }
}

// ============ K4: gather-aggregate layer 2 + head-mean + softmax ============
// Lane = (edge-slot e8, head hd). ONE float4 gather per edge-lane carries the
// head's 3 classes AND the src logit. Fully software-pipelined.
__global__ __launch_bounds__(256) void k_gat2(const int* __restrict__ off,
                                              const int* __restrict__ srt_src,
                                              const float* __restrict__ al2d,
                                              const float* __restrict__ xw2,
                                              const float* __restrict__ b2,
                                              float* __restrict__ out) {
    const int tid = threadIdx.x;
    const int lane = tid & 63;
    const int wid = tid >> 6;
    const int n = blockIdx.x * 4 + wid;
    const int e8 = lane >> 3;
    const int hd = lane & 7;

    const float ald = al2d[n * 8 + hd];
    const int kend = off[n + 1];

    float ax = 0.f, ay = 0.f, az = 0.f, ssum = 0.f;
    int k = off[n] + e8;
    int s = (k < kend) ? srt_src[k] : -1;
    float4 v = make_float4(0.f, 0.f, 0.f, 0.f);
    if (s >= 0) v = *(const float4*)(xw2 + (long)s * D2P + hd * 4);
    while (s >= 0) {
        const int kn = k + 8;
        const int sn = (kn < kend) ? srt_src[kn] : -1;
        float4 vn = v;
        if (sn >= 0) vn = *(const float4*)(xw2 + (long)sn * D2P + hd * 4);
        float ev = v.w + ald;                      // v.w = src logit
        ev = ev > 0.f ? ev : 0.2f * ev;
        const float ex = __expf(ev);
        ax += ex * v.x; ay += ex * v.y; az += ex * v.z;
        ssum += ex;
        k = kn; s = sn; v = vn;
    }
    // reduce across 8 edge slots (bits 3,4,5)
#pragma unroll
    for (int mm = 8; mm < 64; mm <<= 1) {
        ax += __shfl_xor(ax, mm, 64);
        ay += __shfl_xor(ay, mm, 64);
        az += __shfl_xor(az, mm, 64);
        ssum += __shfl_xor(ssum, mm, 64);
    }
    const float inv = 1.0f / (ssum + 1e-16f);
    float mx = ax * inv, my = ay * inv, mz = az * inv;   // this head's alpha-mean
    // head mean: reduce over head bits 0,1,2
#pragma unroll
    for (int mm = 1; mm < 8; mm <<= 1) {
        mx += __shfl_xor(mx, mm, 64);
        my += __shfl_xor(my, mm, 64);
        mz += __shfl_xor(mz, mm, 64);
    }
    const float l0 = mx * 0.125f + b2[0];
    const float l1 = my * 0.125f + b2[1];
    const float l2 = mz * 0.125f + b2[2];
    const float mmax = fmaxf(l0, fmaxf(l1, l2));
    const float ee0 = expf(l0 - mmax), ee1 = expf(l1 - mmax), ee2 = expf(l2 - mmax);
    const float dinv = 1.0f / (ee0 + ee1 + ee2);
    if (lane < 3) {
        const float p = (lane == 0) ? ee0 : (lane == 1) ? ee1 : ee2;
        out[(long)n * 3 + lane] = p * dinv;
    }
}

extern "C" void kernel_launch(void* const* d_in, const int* in_sizes, int n_in,
                              void* d_out, int out_size, void* d_ws, size_t ws_size,
                              hipStream_t stream) {
    const float* x   = (const float*)d_in[0];
    const float* W1  = (const float*)d_in[1];
    const float* a1s = (const float*)d_in[2];
    const float* a1d = (const float*)d_in[3];
    const float* b1  = (const float*)d_in[4];
    const float* W2  = (const float*)d_in[5];
    const float* a2s = (const float*)d_in[6];
    const float* a2d = (const float*)d_in[7];
    const float* b2  = (const float*)d_in[8];
    const int*   ei  = (const int*)d_in[9];
    float* out = (float*)d_out;

    float* ws   = (float*)d_ws;
    float* xw2  = ws;                      // 100000*32 = 3,200,000 floats (tmp overlays)
    float* al1s = xw2  + 3200000;          //   800,000
    float* al1d = al1s + 800000;           //   800,000
    float* al2d = al1d + 800000;           //   800,000
    short* xw1b = (short*)(al2d + 800000); // 6,400,000 shorts (bf16)
    int* off    = (int*)(xw1b + 6400000);  //   100,004 (padded for alignment)
    int* gcnt   = off + 100004;            //   391*32 (line-padded cursors)
    int* srt    = gcnt + NBKT * 32;        // 1,700,000
    short* wT   = (short*)(srt + 1700000); //   64*512 halfs (16B aligned)
    int* tmp    = (int*)xw2;               //   391*5120 = 2,001,920 ints ( < 3.2M )

    k_init<<<64, 256, 0, stream>>>(gcnt, W1, wT);
    k_pg<<<NPB + GEMB, 256, 0, stream>>>(ei, gcnt, tmp, x, wT, a1s, a1d,
                                         xw1b, al1s, al1d);
    k_bucket2<<<NBKT, 512, 0, stream>>>(gcnt, tmp, off, srt);
    k_gat1<<<N_NODESC / 4, 256, 0, stream>>>(off, srt, al1s, al1d, xw1b, b1,
                                             W2, a2s, a2d, xw2, al2d);
    k_gat2<<<N_NODESC / 4, 256, 0, stream>>>(off, srt, al2d, xw2, b2, out);
}